// Round 4
// baseline (522.317 us; speedup 1.0000x reference)
//
#include <hip/hip_runtime.h>

typedef unsigned int u32;
typedef unsigned short u16;
typedef __bf16 bf16x8 __attribute__((ext_vector_type(8)));
typedef float f32x4 __attribute__((ext_vector_type(4)));
typedef u32 u32x4 __attribute__((ext_vector_type(4)));
typedef u32 u32x2 __attribute__((ext_vector_type(2)));

#define NTOK 64
#define CDIM 256
#define NH 8

// ---- workspace layout (u16 units, after 16-byte flag header) ----
#define WS_HDR 8
#define BIAS_O (WS_HDR)             // [8][64][64] expanded bias     (32768)
#define WQKV_O (BIAS_O + 32768)     // w_qkv bf16                    (196608)
#define BQKV_O (WQKV_O + 196608)    // b_qkv bf16                    (768)
#define WPRJ_O (BQKV_O + 768)       // w_proj bf16                   (65536)
#define BPRJ_O (WPRJ_O + 65536)     // b_proj bf16                   (256)

// ---- LDS byte layout (total 138240 B <= 160 KiB) ----
#define XS_OFF 0          // x   [64][264] bf16 (row stride 528 B); dead after stage 1
#define QS_OFF 33792      // q   [64][264] bf16;                    dead after stage 2a
#define KS_OFF 67584      // k   [64][264] bf16; reused as y for stage 4
#define VT_OFF 101376     // vT  [8][32][72] bf16
#define LDS_BYTES 138240
// P   [8][64][64] bf16 (swizzled) overlays XS+QS (bytes 0..65536) after stage 2a
// OUT [64][256] f32 (swizzled)    overlays same region after stage 3

__device__ __forceinline__ float bf2f(u16 u) {
  union { u32 i; float f; } z; z.i = ((u32)u) << 16; return z.f;
}
__device__ __forceinline__ u16 f2bf(float f) {
  __bf16 h = (__bf16)f; return __builtin_bit_cast(u16, h);
}
__device__ __forceinline__ float fetchf(const void* p, int idx, int isbf) {
  return isbf ? bf2f(((const u16*)p)[idx]) : ((const float*)p)[idx];
}

// Classify x buffer: bf16 data -> every u16 is a sane bf16 (exponent near 127);
// f32 data -> even-index u16s are random low mantissa bits (~28% sane). flag=1 means bf16.
__global__ void detect_dtype(const u16* __restrict__ x, int* __restrict__ flag) {
  __shared__ int cnt;
  if (threadIdx.x == 0) cnt = 0;
  __syncthreads();
  int sane = 0;
  for (int i = threadIdx.x; i < 2048; i += 256) {
    u16 u = x[2 * i];
    int e = (u >> 7) & 0xFF;
    sane += (e == 0 || (e >= 90 && e <= 160)) ? 1 : 0;
  }
  atomicAdd(&cnt, sane);
  __syncthreads();
  if (threadIdx.x == 0) *flag = (cnt >= 1638) ? 1 : 0;
}

// Convert all parameters to bf16 in ws; expand relative-position bias to [h][n][m].
__global__ void cvt_params(const void* __restrict__ wqkv, const void* __restrict__ bqkv,
                           const void* __restrict__ btab, const void* __restrict__ wprj,
                           const void* __restrict__ bprj, void* __restrict__ wsraw) {
  u16* ws = (u16*)wsraw;
  const int isbf = *(const int*)wsraw;
  int i = blockIdx.x * 256 + threadIdx.x;
  if (i < 32768) {
    int h = i >> 12, n = (i >> 6) & 63, m = i & 63;
    int r0 = (n >> 3) - (m >> 3) + 7, r1 = (n & 7) - (m & 7) + 7;
    ws[BIAS_O + i] = f2bf(fetchf(btab, (r0 * 15 + r1) * NH + h, isbf));
  } else if (i < 32768 + 196608) {
    int j = i - 32768;
    ws[WQKV_O + j] = f2bf(fetchf(wqkv, j, isbf));
  } else if (i < 32768 + 196608 + 768) {
    int j = i - (32768 + 196608);
    ws[BQKV_O + j] = f2bf(fetchf(bqkv, j, isbf));
  } else if (i < 32768 + 196608 + 768 + 65536) {
    int j = i - (32768 + 196608 + 768);
    ws[WPRJ_O + j] = f2bf(fetchf(wprj, j, isbf));
  } else if (i < 32768 + 196608 + 768 + 65536 + 256) {
    int j = i - (32768 + 196608 + 768 + 65536);
    ws[BPRJ_O + j] = f2bf(fetchf(bprj, j, isbf));
  }
}

__global__ __launch_bounds__(512, 2)
void win_attn_fused(const void* __restrict__ xraw, const void* __restrict__ wsraw,
                    float* __restrict__ out)
{
  __shared__ __align__(16) unsigned char lds[LDS_BYTES];
  const u16* ws  = (const u16*)wsraw;
  const int isbf = *(const int*)wsraw;      // block-uniform
  const int b    = blockIdx.x;
  const int tid  = threadIdx.x;
  const int w    = tid >> 6;     // wave id = head id
  const int lane = tid & 63;
  const int c    = lane & 15;    // MFMA col / A-row lane index
  const int g    = lane >> 4;    // lane group

  // ---- stage 0: x[b] (64x256) -> XS bf16 (row stride 528 B)
  if (isbf) {
    const u32x4* gx = (const u32x4*)((const u16*)xraw + (size_t)b * (NTOK * CDIM));
#pragma unroll
    for (int i = 0; i < 4; ++i) {
      int q = tid + i * 512;            // 2048 16-byte chunks
      int row = q >> 5, c8 = q & 31;
      *(u32x4*)(lds + XS_OFF + row * 528 + c8 * 16) = gx[q];
    }
  } else {
    const f32x4* gx = (const f32x4*)((const float*)xraw + (size_t)b * (NTOK * CDIM));
#pragma unroll
    for (int i = 0; i < 8; ++i) {
      int q = tid + i * 512;            // 4096 16-byte f32 chunks
      int row = q >> 6, c4 = q & 63;
      f32x4 v = gx[q];
      u32x2 pk;
      pk[0] = (u32)f2bf(v[0]) | ((u32)f2bf(v[1]) << 16);
      pk[1] = (u32)f2bf(v[2]) | ((u32)f2bf(v[3]) << 16);
      *(u32x2*)(lds + XS_OFF + row * 528 + c4 * 8) = pk;
    }
  }
  __syncthreads();

  const float scale = 0.1767766952966369f;  // 32^-0.5

  // ---- stage 1: qkv = x @ w_qkv^T + b_qkv ; wave w -> cols [96w, 96w+96)
  for (int jt = 0; jt < 6; ++jt) {
    const int jc   = w * 96 + jt * 16;   // wave-uniform
    const int colw = jc + c;             // output column (row of w_qkv)
    f32x4 acc[4] = {{0,0,0,0},{0,0,0,0},{0,0,0,0},{0,0,0,0}};
    const u16* wrow = ws + WQKV_O + colw * CDIM;
#pragma unroll
    for (int ks = 0; ks < 8; ++ks) {
      bf16x8 bf = *(const bf16x8*)(wrow + ks * 32 + g * 8);
#pragma unroll
      for (int rt = 0; rt < 4; ++rt) {
        bf16x8 af = *(const bf16x8*)(lds + XS_OFF + (16 * rt + c) * 528 + ks * 64 + g * 16);
        acc[rt] = __builtin_amdgcn_mfma_f32_16x16x32_bf16(af, bf, acc[rt], 0, 0, 0);
      }
    }
    const float badd = bf2f(ws[BQKV_O + colw]);
#pragma unroll
    for (int rt = 0; rt < 4; ++rt) {
#pragma unroll
      for (int reg = 0; reg < 4; ++reg) {
        int r = 16 * rt + 4 * g + reg;        // token index
        float val = acc[rt][reg] + badd;
        if (jc < 256) {                       // q (scale folded in)
          *(u16*)(lds + QS_OFF + r * 528 + colw * 2) = f2bf(val * scale);
        } else if (jc < 512) {                // k
          *(u16*)(lds + KS_OFF + r * 528 + (colw - 256) * 2) = f2bf(val);
        } else {                              // v -> transposed vT[h][d][m]
          int cc = colw - 512, hd = cc >> 5, dd = cc & 31;
          *(u16*)(lds + VT_OFF + hd * 4608 + dd * 144 + r * 2) = f2bf(val);
        }
      }
    }
  }
  __syncthreads();

  // ---- stage 2a: S = (q*scale) @ k^T + bias[h]  (accumulator pre-loaded with bias)
  const int h = w;
  f32x4 s[4][4];
#pragma unroll
  for (int rt = 0; rt < 4; ++rt)
#pragma unroll
    for (int ct = 0; ct < 4; ++ct)
#pragma unroll
      for (int reg = 0; reg < 4; ++reg) {
        int n = 16 * rt + 4 * g + reg, m = 16 * ct + c;
        s[rt][ct][reg] = bf2f(ws[BIAS_O + (h << 12) + (n << 6) + m]);
      }
  {
    bf16x8 aq[4], bk[4];
#pragma unroll
    for (int rt = 0; rt < 4; ++rt)
      aq[rt] = *(const bf16x8*)(lds + QS_OFF + (16 * rt + c) * 528 + h * 64 + g * 16);
#pragma unroll
    for (int ct = 0; ct < 4; ++ct)
      bk[ct] = *(const bf16x8*)(lds + KS_OFF + (16 * ct + c) * 528 + h * 64 + g * 16);
#pragma unroll
    for (int rt = 0; rt < 4; ++rt)
#pragma unroll
      for (int ct = 0; ct < 4; ++ct)
        s[rt][ct] = __builtin_amdgcn_mfma_f32_16x16x32_bf16(aq[rt], bk[ct], s[rt][ct], 0, 0, 0);
  }

  // ---- softmax over rows (row n lives in the 16 lanes of group g=(n>>2)&3)
#pragma unroll
  for (int rt = 0; rt < 4; ++rt) {
#pragma unroll
    for (int reg = 0; reg < 4; ++reg) {
      float v0 = s[rt][0][reg], v1 = s[rt][1][reg], v2 = s[rt][2][reg], v3 = s[rt][3][reg];
      float mx = fmaxf(fmaxf(v0, v1), fmaxf(v2, v3));
#pragma unroll
      for (int i = 1; i < 16; i <<= 1) mx = fmaxf(mx, __shfl_xor(mx, i));
      v0 = __expf(v0 - mx); v1 = __expf(v1 - mx);
      v2 = __expf(v2 - mx); v3 = __expf(v3 - mx);
      float sm = v0 + v1 + v2 + v3;
#pragma unroll
      for (int i = 1; i < 16; i <<= 1) sm += __shfl_xor(sm, i);
      float inv = 1.0f / sm;
      s[rt][0][reg] = v0 * inv; s[rt][1][reg] = v1 * inv;
      s[rt][2][reg] = v2 * inv; s[rt][3][reg] = v3 * inv;
    }
  }
  __syncthreads();   // all waves done reading QS/KS; P may now overlay XS/QS

  // ---- stage 2b: P -> LDS (row = 128 B, XOR-swizzled to kill 32-way conflicts)
  const int Pb = w * 8192;
#pragma unroll
  for (int rt = 0; rt < 4; ++rt)
#pragma unroll
    for (int ct = 0; ct < 4; ++ct)
#pragma unroll
      for (int reg = 0; reg < 4; ++reg) {
        int r = 16 * rt + 4 * g + reg, cc = 16 * ct + c;
        int byte = (r * 128 + cc * 2) ^ ((r & 7) << 4);
        *(u16*)(lds + Pb + byte) = f2bf(s[rt][ct][reg]);
      }
  __syncthreads();   // defensive fence between u16 P writes and bf16x8 P reads

  // ---- stage 3: y_h = P @ v_h   (A = P from LDS, B = vT rows, both contiguous)
  f32x4 o[4][2] = {{{0,0,0,0},{0,0,0,0}},{{0,0,0,0},{0,0,0,0}},
                   {{0,0,0,0},{0,0,0,0}},{{0,0,0,0},{0,0,0,0}}};
#pragma unroll
  for (int ks = 0; ks < 2; ++ks) {
    bf16x8 ap[4], bv[2];
#pragma unroll
    for (int rt = 0; rt < 4; ++rt) {
      int r = 16 * rt + c;
      int byte = (r * 128 + ks * 64 + g * 16) ^ ((r & 7) << 4);
      ap[rt] = *(const bf16x8*)(lds + Pb + byte);
    }
#pragma unroll
    for (int ct = 0; ct < 2; ++ct)
      bv[ct] = *(const bf16x8*)(lds + VT_OFF + h * 4608 + (16 * ct + c) * 144 + ks * 64 + g * 16);
#pragma unroll
    for (int rt = 0; rt < 4; ++rt)
#pragma unroll
      for (int ct = 0; ct < 2; ++ct)
        o[rt][ct] = __builtin_amdgcn_mfma_f32_16x16x32_bf16(ap[rt], bv[ct], o[rt][ct], 0, 0, 0);
  }
  // y[n][h*32+dd] into KS region (k is dead; per-wave column ranges disjoint)
#pragma unroll
  for (int rt = 0; rt < 4; ++rt)
#pragma unroll
    for (int ct = 0; ct < 2; ++ct)
#pragma unroll
      for (int reg = 0; reg < 4; ++reg) {
        int n = 16 * rt + 4 * g + reg;
        int col = h * 32 + 16 * ct + c;
        *(u16*)(lds + KS_OFF + n * 528 + col * 2) = f2bf(o[rt][ct][reg]);
      }
  __syncthreads();   // y ready; P region now dead -> OUT tile may overlay it

  // ---- stage 4: out = y @ w_proj^T + b_proj ; wave w -> cols [32w, 32w+32)
#pragma unroll
  for (int ct = 0; ct < 2; ++ct) {
    const int colw = w * 32 + ct * 16 + c;
    const float badd = bf2f(ws[BPRJ_O + colw]);
    f32x4 acc[4];
#pragma unroll
    for (int rt = 0; rt < 4; ++rt)
#pragma unroll
      for (int reg = 0; reg < 4; ++reg) acc[rt][reg] = badd;
    const u16* wrow = ws + WPRJ_O + colw * CDIM;
#pragma unroll
    for (int ks = 0; ks < 8; ++ks) {
      bf16x8 bf = *(const bf16x8*)(wrow + ks * 32 + g * 8);
#pragma unroll
      for (int rt = 0; rt < 4; ++rt) {
        bf16x8 af = *(const bf16x8*)(lds + KS_OFF + (16 * rt + c) * 528 + ks * 64 + g * 16);
        acc[rt] = __builtin_amdgcn_mfma_f32_16x16x32_bf16(af, bf, acc[rt], 0, 0, 0);
      }
    }
    // stage OUT tile [64][256] f32 in LDS (overlays dead P region, bytes 0..65536);
    // swizzle byte ^= ((n>>2)&3)<<6 -> only a free 2-way bank alias on write
#pragma unroll
    for (int rt = 0; rt < 4; ++rt)
#pragma unroll
      for (int reg = 0; reg < 4; ++reg) {
        int n = 16 * rt + 4 * g + reg;
        int byte = (n * 1024 + colw * 4) ^ (((n >> 2) & 3) << 6);
        *(float*)(lds + byte) = acc[rt][reg];
      }
  }
  __syncthreads();

  // ---- coalesced f32x4 store: 4096 chunks of 16 B, 1 KB per wave-instruction
  float* gout = out + (size_t)b * (NTOK * CDIM);
#pragma unroll
  for (int i = 0; i < 8; ++i) {
    int q = tid + i * 512;
    int row = q >> 6, c16 = q & 63;
    f32x4 v = *(const f32x4*)(lds + ((row * 1024 + c16 * 16) ^ (((row >> 2) & 3) << 6)));
    *(f32x4*)(gout + row * CDIM + c16 * 4) = v;
  }
}

extern "C" void kernel_launch(void* const* d_in, const int* in_sizes, int n_in,
                              void* d_out, int out_size, void* d_ws, size_t ws_size,
                              hipStream_t stream) {
  (void)in_sizes; (void)n_in; (void)out_size; (void)ws_size;
  detect_dtype<<<dim3(1), dim3(256), 0, stream>>>((const u16*)d_in[0], (int*)d_ws);
  cvt_params<<<dim3(1156), dim3(256), 0, stream>>>(d_in[1], d_in[2], d_in[3], d_in[4],
                                                   d_in[5], d_ws);
  win_attn_fused<<<dim3(4096), dim3(512), 0, stream>>>(d_in[0], d_ws, (float*)d_out);
}